// Round 9
// baseline (2507.405 us; speedup 1.0000x reference)
//
#include <hip/hip_runtime.h>

// GraphAttention (e3nn-style) on MI355X — Round 9: R4 pipeline (proven 346us)
// + MFMA diagnostic probes (output-neutral; report via rocprof dur/Kernel_Name).
// R7/R8 failed with output==0 (stub signature) and no counters; probes convert
// that opaque failure into per-stage evidence using spin-on-mismatch timing.
//
// Dims: M0=16 M1=8 Q0=8 Q1=4 O0=16 O1=8 EB=16 H=32
// TPK [32][320]: w1[0,128) w2[128,192) w3[192,256) w4[256,288) w5[288,320)
// TPV [32][640]: w1[0,256) w2[256,384) w3[384,512) w4[512,576) w5[576,640)
//
// ws (4B): qd[N*20] | cnt[N] | start[N+1] | cursor[N] | flag | pad |
//          exbuf[E] | sabuf[E] | posbuf[E] | vbuf[E*40] | probe_scratch[1024]

#define BS 256

typedef __attribute__((ext_vector_type(8))) short bf16x8;
typedef __attribute__((ext_vector_type(4))) float f32x4;
union ABu { unsigned u[4]; bf16x8 v; };

__device__ __forceinline__ float silu_f(float x) {
    return x * (1.0f / (1.0f + __expf(-x)));
}
__device__ __forceinline__ unsigned short f2b(float f) {   // f32 -> bf16 (RNE)
    unsigned u = __float_as_uint(f);
    u += 0x7fffu + ((u >> 16) & 1u);
    return (unsigned short)(u >> 16);
}
__device__ __forceinline__ float b2f(unsigned short h) {
    return __uint_as_float(((unsigned)h) << 16);
}
__device__ __forceinline__ unsigned pack2(float a, float b) {   // a=low, b=high
    return ((unsigned)f2b(b) << 16) | (unsigned)f2b(a);
}
__device__ __forceinline__ float bsel(unsigned u, int hi) {     // bf16 pair select
    return hi ? __uint_as_float(u & 0xffff0000u) : __uint_as_float(u << 16);
}
__device__ __forceinline__ void spin_fma(int iters, float* sink) {
    float x = 1.0f;
#pragma unroll 1
    for (int i = 0; i < iters; ++i) x = fmaf(x, 1.0000001f, 1.0e-9f);
    if (x == 123.456f) *sink = x;   // never true; keeps the loop alive
}

// ---------------- R4 pipeline (validated: 346us pass), verbatim ----------------
__global__ __launch_bounds__(256) void node_pre(
    const float* __restrict__ node_ft,
    const int*   __restrict__ ei,
    const float* __restrict__ w_q_s, const float* __restrict__ w_q_v,
    const float* __restrict__ wdot_s, const float* __restrict__ wdot_v,
    float* __restrict__ qd, int* __restrict__ cnt, int* __restrict__ flag,
    int N, int E)
{
    const int n = blockIdx.x * blockDim.x + threadIdx.x;
    if (n == 0) {
        int acc = 0;
        const int kmax = (E < 64) ? E : 64;
        for (int k = 0; k < kmax; ++k) acc |= ei[2*k + 1];
        *flag = (acc == 0) ? 1 : 0;   // int64 layout => odd words all zero
    }
    if (n >= N) return;
    cnt[n] = 0;

    const float* nf = node_ft + (size_t)n * 40;
    float xs[16];
#pragma unroll
    for (int i = 0; i < 16; ++i) xs[i] = nf[i];
    float q[8];
#pragma unroll
    for (int o = 0; o < 8; ++o) {
        float a = 0.f;
#pragma unroll
        for (int i = 0; i < 16; ++i) a += xs[i] * w_q_s[i*8 + o];
        q[o] = a * 0.25f;
    }
    float* qdn = qd + (size_t)n * 20;
#pragma unroll
    for (int j = 0; j < 8; ++j) {
        float a = 0.f;
#pragma unroll
        for (int i = 0; i < 8; ++i) a += q[i] * wdot_s[i*8 + j];
        qdn[j] = a;
    }
    float xv[8][3];
#pragma unroll
    for (int i = 0; i < 8; ++i)
#pragma unroll
        for (int c = 0; c < 3; ++c) xv[i][c] = nf[16 + i*3 + c];
    float qv[4][3];
#pragma unroll
    for (int o = 0; o < 4; ++o)
#pragma unroll
        for (int c = 0; c < 3; ++c) {
            float a = 0.f;
#pragma unroll
            for (int i = 0; i < 8; ++i) a += xv[i][c] * w_q_v[i*4 + o];
            qv[o][c] = a * 0.35355339059327379f;
        }
#pragma unroll
    for (int j = 0; j < 4; ++j)
#pragma unroll
        for (int c = 0; c < 3; ++c) {
            float a = 0.f;
#pragma unroll
            for (int i = 0; i < 4; ++i) a += qv[i][c] * wdot_v[i*4 + j];
            qdn[8 + j*3 + c] = a;
        }
}

__global__ __launch_bounds__(256) void count_edges(
    const int* __restrict__ ei, int* __restrict__ cnt,
    const int* __restrict__ flag, int E)
{
    const int e = blockIdx.x * blockDim.x + threadIdx.x;
    if (e >= E) return;
    const int is64 = *flag;
    const int rcv = is64 ? ei[2*(E + e)] : ei[E + e];
    atomicAdd(cnt + rcv, 1);
}

__global__ __launch_bounds__(1024) void scan_kernel(
    const int* __restrict__ cnt, int* __restrict__ start,
    int* __restrict__ cursor, int N)
{
    __shared__ int wsum[16];
    __shared__ int s_carry;
    const int tid = threadIdx.x, wave = tid >> 6, lane = tid & 63;
    if (tid == 0) s_carry = 0;
    __syncthreads();
    for (int base = 0; base < N; base += 1024) {
        const int i = base + tid;
        const int v = (i < N) ? cnt[i] : 0;
        int x = v;
#pragma unroll
        for (int d = 1; d < 64; d <<= 1) {
            const int y = __shfl_up(x, d, 64);
            if (lane >= d) x += y;
        }
        if (lane == 63) wsum[wave] = x;
        __syncthreads();
        if (wave == 0 && lane < 16) {
            int w = wsum[lane];
#pragma unroll
            for (int d = 1; d < 16; d <<= 1) {
                const int y = __shfl_up(w, d, 64);
                if (lane >= d) w += y;
            }
            wsum[lane] = w;
        }
        __syncthreads();
        const int woff = (wave == 0) ? 0 : wsum[wave - 1];
        const int carry = s_carry;
        if (i < N) {
            const int s = carry + woff + x - v;
            start[i] = s;
            cursor[i] = s;
        }
        __syncthreads();
        if (tid == 0) s_carry = carry + wsum[15];
        __syncthreads();
    }
    if (tid == 0) start[N] = s_carry;
}

__global__ __launch_bounds__(BS) void edge_k(
    const float* __restrict__ node_ft,
    const int*   __restrict__ ei,
    const float* __restrict__ edge_sh,
    const float* __restrict__ edge_scalars,
    const float* __restrict__ fck_w1,       // [16,32] global (s_load)
    const float* __restrict__ fck_w2,       // [32,320] -> LDS
    const float* __restrict__ qd,
    int*   __restrict__ cursor,
    float* __restrict__ exbuf,              // [E] CSR order
    float* __restrict__ sabuf,              // [E] edge order
    int*   __restrict__ posbuf,             // [E] edge order
    const int* __restrict__ flag,
    int N, int E)
{
    __shared__ float sW[32 * 320];                      // 40 KB
    __shared__ unsigned short s_xs[16][BS];             // 8 KB  (bf16 cols)
    __shared__ unsigned short s_xv[3][8][BS];           // 12 KB (bf16 cols)

    const int tid = threadIdx.x;
    for (int idx = tid; idx < 32 * 320; idx += BS) sW[idx] = fck_w2[idx];
    __syncthreads();

    const int e = blockIdx.x * BS + tid;
    if (e >= E) return;   // no barriers below

    const int is64 = *flag;
    const int snd = is64 ? ei[2*e]       : ei[e];
    const int rcv = is64 ? ei[2*(E + e)] : ei[E + e];

    const int pos = atomicAdd(cursor + rcv, 1);

    const float4 sh4 = *(const float4*)(edge_sh + (size_t)e * 4);
    const float shs = sh4.x;
    const float shv0 = sh4.y, shv1 = sh4.z, shv2 = sh4.w;

    {
        const float4* nf4 = (const float4*)(node_ft + (size_t)snd * 40);
        float xb[40];
#pragma unroll
        for (int t = 0; t < 10; ++t) {
            const float4 v = nf4[t];
            xb[4*t+0] = v.x; xb[4*t+1] = v.y; xb[4*t+2] = v.z; xb[4*t+3] = v.w;
        }
#pragma unroll
        for (int i = 0; i < 16; ++i) s_xs[i][tid] = f2b(xb[i]);
#pragma unroll
        for (int i = 0; i < 8; ++i)
#pragma unroll
            for (int c = 0; c < 3; ++c) s_xv[c][i][tid] = f2b(xb[16 + i*3 + c]);
    }

    float es[16];
    {
        const float4* esp = (const float4*)(edge_scalars + (size_t)e * 16);
#pragma unroll
        for (int t = 0; t < 4; ++t) {
            const float4 v = esp[t];
            es[4*t+0] = v.x; es[4*t+1] = v.y; es[4*t+2] = v.z; es[4*t+3] = v.w;
        }
    }

    float hk[32];
#pragma unroll
    for (int j = 0; j < 32; ++j) {
        float a = 0.f;
#pragma unroll
        for (int t = 0; t < 16; ++t) a += es[t] * fck_w1[t*32 + j];
        hk[j] = silu_f(a * 0.25f);
    }

    float tk1[8] = {}, tk3[4] = {};
#pragma unroll 1
    for (int i = 0; i < 16; ++i) {
        const float xsi = b2f(s_xs[i][tid]);
#pragma unroll
        for (int j = 0; j < 32; ++j) {
            const float t = xsi * hk[j];
            const float4 a = *(const float4*)&sW[j*320 + i*8];
            const float4 b = *(const float4*)&sW[j*320 + i*8 + 4];
            const float4 c = *(const float4*)&sW[j*320 + 192 + i*4];
            tk1[0] += t*a.x; tk1[1] += t*a.y; tk1[2] += t*a.z; tk1[3] += t*a.w;
            tk1[4] += t*b.x; tk1[5] += t*b.y; tk1[6] += t*b.z; tk1[7] += t*b.w;
            tk3[0] += t*c.x; tk3[1] += t*c.y; tk3[2] += t*c.z; tk3[3] += t*c.w;
        }
    }

    float tk2[8] = {};
#pragma unroll 1
    for (int i = 0; i < 8; ++i) {
        const float pv = (b2f(s_xv[0][i][tid])*shv0 + b2f(s_xv[1][i][tid])*shv1 +
                          b2f(s_xv[2][i][tid])*shv2) * 0.57735026918962576f;
#pragma unroll
        for (int j = 0; j < 32; ++j) {
            const float t = pv * hk[j];
            const float4 a = *(const float4*)&sW[j*320 + 128 + i*8];
            const float4 b = *(const float4*)&sW[j*320 + 128 + i*8 + 4];
            tk2[0] += t*a.x; tk2[1] += t*a.y; tk2[2] += t*a.z; tk2[3] += t*a.w;
            tk2[4] += t*b.x; tk2[5] += t*b.y; tk2[6] += t*b.z; tk2[7] += t*b.w;
        }
    }

    float tk4[4][3] = {}, tk5[4][3] = {};
#pragma unroll 1
    for (int i = 0; i < 8; ++i) {
        float w4[4] = {}, w5[4] = {};
#pragma unroll
        for (int j = 0; j < 32; ++j) {
            const float hj = hk[j];
            const float4 a = *(const float4*)&sW[j*320 + 256 + i*4];
            const float4 b = *(const float4*)&sW[j*320 + 288 + i*4];
            w4[0] += hj*a.x; w4[1] += hj*a.y; w4[2] += hj*a.z; w4[3] += hj*a.w;
            w5[0] += hj*b.x; w5[1] += hj*b.y; w5[2] += hj*b.z; w5[3] += hj*b.w;
        }
        const float x0 = b2f(s_xv[0][i][tid]);
        const float x1 = b2f(s_xv[1][i][tid]);
        const float x2 = b2f(s_xv[2][i][tid]);
#pragma unroll
        for (int o = 0; o < 4; ++o) {
            tk4[o][0] += x0*w4[o]; tk4[o][1] += x1*w4[o]; tk4[o][2] += x2*w4[o];
            tk5[o][0] += x0*w5[o]; tk5[o][1] += x1*w5[o]; tk5[o][2] += x2*w5[o];
        }
    }

    float qdr[20];
    {
        const float4* qp = (const float4*)(qd + (size_t)rcv * 20);
#pragma unroll
        for (int t = 0; t < 5; ++t) {
            const float4 v = qp[t];
            qdr[4*t+0] = v.x; qdr[4*t+1] = v.y; qdr[4*t+2] = v.z; qdr[4*t+3] = v.w;
        }
    }
    float dots = 0.f, dotv = 0.f;
#pragma unroll
    for (int o = 0; o < 8; ++o) dots += qdr[o] * (shs*tk1[o] + tk2[o]);
    const float shv_[3] = {shv0, shv1, shv2};
#pragma unroll
    for (int o = 0; o < 4; ++o)
#pragma unroll
        for (int c = 0; c < 3; ++c) {
            const int c1 = (c+1) % 3, c2 = (c+2) % 3;
            const float kv = tk3[o]*shv_[c] + shs*tk4[o][c]
                + (shv_[c2]*tk5[o][c1] - shv_[c1]*tk5[o][c2]) * 0.70710678118654752f;
            dotv += qdr[8 + o*3 + c] * kv;
        }
    const float dot = dots * 4.0343567508008e-3f + dotv * 2.0171788261497e-3f;

    const float sa = __expf(0.5f * dot);
    exbuf[pos] = sa * sa;          // exp(dot)
    sabuf[e]   = sa;               // sqrt(exp(dot))
    posbuf[e]  = pos;
}

__global__ __launch_bounds__(BS) void edge_v_a(
    const float* __restrict__ node_ft,
    const int*   __restrict__ ei,
    const float* __restrict__ edge_sh,
    const float* __restrict__ edge_scalars,
    const float* __restrict__ fcv_w1,
    const float* __restrict__ fcv_w2,
    const float* __restrict__ sabuf,
    const int*   __restrict__ posbuf,
    float* __restrict__ vbuf,               // [E,40]
    const int* __restrict__ flag,
    int E)
{
    __shared__ float sW[32 * 384];                      // 48 KB
    __shared__ unsigned short s_xs[16][BS];             // 8 KB
    __shared__ unsigned short s_pv[8][BS];              // 4 KB

    const int tid = threadIdx.x;
#pragma unroll 1
    for (int j = 0; j < 32; ++j)
        for (int c = tid; c < 384; c += BS) sW[j*384 + c] = fcv_w2[j*640 + c];
    __syncthreads();

    const int e = blockIdx.x * BS + tid;
    if (e >= E) return;

    const int is64 = *flag;
    const int snd = is64 ? ei[2*e] : ei[e];

    const float4 sh4 = *(const float4*)(edge_sh + (size_t)e * 4);
    const float shs = sh4.x;

    {
        const float4* nf4 = (const float4*)(node_ft + (size_t)snd * 40);
        float xb[40];
#pragma unroll
        for (int t = 0; t < 10; ++t) {
            const float4 v = nf4[t];
            xb[4*t+0] = v.x; xb[4*t+1] = v.y; xb[4*t+2] = v.z; xb[4*t+3] = v.w;
        }
#pragma unroll
        for (int i = 0; i < 16; ++i) s_xs[i][tid] = f2b(xb[i]);
#pragma unroll
        for (int i = 0; i < 8; ++i) {
            const float pv = (xb[16+i*3]*sh4.y + xb[17+i*3]*sh4.z + xb[18+i*3]*sh4.w)
                             * 0.57735026918962576f;
            s_pv[i][tid] = f2b(pv);
        }
    }

    float es[16];
    {
        const float4* esp = (const float4*)(edge_scalars + (size_t)e * 16);
#pragma unroll
        for (int t = 0; t < 4; ++t) {
            const float4 v = esp[t];
            es[4*t+0] = v.x; es[4*t+1] = v.y; es[4*t+2] = v.z; es[4*t+3] = v.w;
        }
    }
    float hv[32];
#pragma unroll
    for (int j = 0; j < 32; ++j) {
        float a = 0.f;
#pragma unroll
        for (int t = 0; t < 16; ++t) a += es[t] * fcv_w1[t*32 + j];
        hv[j] = silu_f(a * 0.25f);
    }

    float tv1[16] = {};
#pragma unroll 1
    for (int i = 0; i < 16; ++i) {
        const float xsi = b2f(s_xs[i][tid]);
#pragma unroll
        for (int j = 0; j < 32; ++j) {
            const float t = xsi * hv[j];
            const float4 a = *(const float4*)&sW[j*384 + i*16];
            const float4 b = *(const float4*)&sW[j*384 + i*16 + 4];
            const float4 c = *(const float4*)&sW[j*384 + i*16 + 8];
            const float4 d = *(const float4*)&sW[j*384 + i*16 + 12];
            tv1[0]  += t*a.x; tv1[1]  += t*a.y; tv1[2]  += t*a.z; tv1[3]  += t*a.w;
            tv1[4]  += t*b.x; tv1[5]  += t*b.y; tv1[6]  += t*b.z; tv1[7]  += t*b.w;
            tv1[8]  += t*c.x; tv1[9]  += t*c.y; tv1[10] += t*c.z; tv1[11] += t*c.w;
            tv1[12] += t*d.x; tv1[13] += t*d.y; tv1[14] += t*d.z; tv1[15] += t*d.w;
        }
    }
    float tv2[16] = {};
#pragma unroll 1
    for (int i = 0; i < 8; ++i) {
        const float pv = b2f(s_pv[i][tid]);
#pragma unroll
        for (int j = 0; j < 32; ++j) {
            const float t = pv * hv[j];
            const float4 a = *(const float4*)&sW[j*384 + 256 + i*16];
            const float4 b = *(const float4*)&sW[j*384 + 256 + i*16 + 4];
            const float4 c = *(const float4*)&sW[j*384 + 256 + i*16 + 8];
            const float4 d = *(const float4*)&sW[j*384 + 256 + i*16 + 12];
            tv2[0]  += t*a.x; tv2[1]  += t*a.y; tv2[2]  += t*a.z; tv2[3]  += t*a.w;
            tv2[4]  += t*b.x; tv2[5]  += t*b.y; tv2[6]  += t*b.z; tv2[7]  += t*b.w;
            tv2[8]  += t*c.x; tv2[9]  += t*c.y; tv2[10] += t*c.z; tv2[11] += t*c.w;
            tv2[12] += t*d.x; tv2[13] += t*d.y; tv2[14] += t*d.z; tv2[15] += t*d.w;
        }
    }

    const float sa = sabuf[e];
    const int pos = posbuf[e];
    const float cs_out = 0.03608439182435161f;   // (1/sqrt32)*(1/sqrt24)
    float4* vp = (float4*)(vbuf + (size_t)pos * 40);
#pragma unroll
    for (int t = 0; t < 4; ++t) {
        float4 r;
        r.x = sa * (shs*tv1[4*t+0] + tv2[4*t+0]) * cs_out;
        r.y = sa * (shs*tv1[4*t+1] + tv2[4*t+1]) * cs_out;
        r.z = sa * (shs*tv1[4*t+2] + tv2[4*t+2]) * cs_out;
        r.w = sa * (shs*tv1[4*t+3] + tv2[4*t+3]) * cs_out;
        vp[t] = r;
    }
}

__global__ __launch_bounds__(BS) void edge_v_b(
    const float* __restrict__ node_ft,
    const int*   __restrict__ ei,
    const float* __restrict__ edge_sh,
    const float* __restrict__ edge_scalars,
    const float* __restrict__ fcv_w1,
    const float* __restrict__ fcv_w2,
    const float* __restrict__ sabuf,
    const int*   __restrict__ posbuf,
    float* __restrict__ vbuf,               // [E,40]
    const int* __restrict__ flag,
    int E)
{
    __shared__ float sW[32 * 256];                      // 32 KB
    __shared__ unsigned short s_xs[16][BS];             // 8 KB
    __shared__ unsigned short s_xv[3][8][BS];           // 12 KB

    const int tid = threadIdx.x;
#pragma unroll 1
    for (int j = 0; j < 32; ++j)
        for (int c = tid; c < 256; c += BS) sW[j*256 + c] = fcv_w2[j*640 + 384 + c];
    __syncthreads();

    const int e = blockIdx.x * BS + tid;
    if (e >= E) return;

    const int is64 = *flag;
    const int snd = is64 ? ei[2*e] : ei[e];

    const float4 sh4 = *(const float4*)(edge_sh + (size_t)e * 4);
    const float shs = sh4.x;
    const float shv_[3] = {sh4.y, sh4.z, sh4.w};

    {
        const float4* nf4 = (const float4*)(node_ft + (size_t)snd * 40);
        float xb[40];
#pragma unroll
        for (int t = 0; t < 10; ++t) {
            const float4 v = nf4[t];
            xb[4*t+0] = v.x; xb[4*t+1] = v.y; xb[4*t+2] = v.z; xb[4*t+3] = v.w;
        }
#pragma unroll
        for (int i = 0; i < 16; ++i) s_xs[i][tid] = f2b(xb[i]);
#pragma unroll
        for (int i = 0; i < 8; ++i)
#pragma unroll
            for (int c = 0; c < 3; ++c) s_xv[c][i][tid] = f2b(xb[16 + i*3 + c]);
    }

    float es[16];
    {
        const float4* esp = (const float4*)(edge_scalars + (size_t)e * 16);
#pragma unroll
        for (int t = 0; t < 4; ++t) {
            const float4 v = esp[t];
            es[4*t+0] = v.x; es[4*t+1] = v.y; es[4*t+2] = v.z; es[4*t+3] = v.w;
        }
    }
    float hv[32];
#pragma unroll
    for (int j = 0; j < 32; ++j) {
        float a = 0.f;
#pragma unroll
        for (int t = 0; t < 16; ++t) a += es[t] * fcv_w1[t*32 + j];
        hv[j] = silu_f(a * 0.25f);
    }

    float tv3[8] = {};
#pragma unroll 1
    for (int i = 0; i < 16; ++i) {
        const float xsi = b2f(s_xs[i][tid]);
#pragma unroll
        for (int j = 0; j < 32; ++j) {
            const float t = xsi * hv[j];
            const float4 a = *(const float4*)&sW[j*256 + i*8];
            const float4 b = *(const float4*)&sW[j*256 + i*8 + 4];
            tv3[0] += t*a.x; tv3[1] += t*a.y; tv3[2] += t*a.z; tv3[3] += t*a.w;
            tv3[4] += t*b.x; tv3[5] += t*b.y; tv3[6] += t*b.z; tv3[7] += t*b.w;
        }
    }

    float tv4[8][3] = {}, tv5[8][3] = {};
#pragma unroll 1
    for (int i = 0; i < 8; ++i) {
        float w4[8] = {}, w5[8] = {};
#pragma unroll
        for (int j = 0; j < 32; ++j) {
            const float hj = hv[j];
            const float4 a = *(const float4*)&sW[j*256 + 128 + i*8];
            const float4 b = *(const float4*)&sW[j*256 + 128 + i*8 + 4];
            const float4 c = *(const float4*)&sW[j*256 + 192 + i*8];
            const float4 d = *(const float4*)&sW[j*256 + 192 + i*8 + 4];
            w4[0] += hj*a.x; w4[1] += hj*a.y; w4[2] += hj*a.z; w4[3] += hj*a.w;
            w4[4] += hj*b.x; w4[5] += hj*b.y; w4[6] += hj*b.z; w4[7] += hj*b.w;
            w5[0] += hj*c.x; w5[1] += hj*c.y; w5[2] += hj*c.z; w5[3] += hj*c.w;
            w5[4] += hj*d.x; w5[5] += hj*d.y; w5[6] += hj*d.z; w5[7] += hj*d.w;
        }
        const float x0 = b2f(s_xv[0][i][tid]);
        const float x1 = b2f(s_xv[1][i][tid]);
        const float x2 = b2f(s_xv[2][i][tid]);
#pragma unroll
        for (int o = 0; o < 8; ++o) {
            tv4[o][0] += x0*w4[o]; tv4[o][1] += x1*w4[o]; tv4[o][2] += x2*w4[o];
            tv5[o][0] += x0*w5[o]; tv5[o][1] += x1*w5[o]; tv5[o][2] += x2*w5[o];
        }
    }

    const float sa = sabuf[e];
    const int pos = posbuf[e];
    float row[24];
#pragma unroll
    for (int o = 0; o < 8; ++o)
#pragma unroll
        for (int c = 0; c < 3; ++c) {
            const int c1 = (c+1) % 3, c2 = (c+2) % 3;
            const float vv = (tv3[o]*shv_[c] + shs*tv4[o][c]
                + (shv_[c2]*tv5[o][c1] - shv_[c1]*tv5[o][c2]) * 0.70710678118654752f)
                * 0.03125f;                      // (1/sqrt32)*(1/sqrt32)
            row[o*3 + c] = sa * vv;
        }
    float4* vp = (float4*)(vbuf + (size_t)pos * 40 + 16);
#pragma unroll
    for (int t = 0; t < 6; ++t) {
        float4 r;
        r.x = row[4*t+0]; r.y = row[4*t+1]; r.z = row[4*t+2]; r.w = row[4*t+3];
        vp[t] = r;
    }
}

__global__ __launch_bounds__(256) void node_reduce(
    const int*   __restrict__ start,
    const float* __restrict__ exbuf,
    const float* __restrict__ vbuf,
    float* __restrict__ out, int N)
{
    const int wave = threadIdx.x >> 6;
    const int lane = threadIdx.x & 63;
    const int n = blockIdx.x * 4 + wave;
    if (n >= N) return;
    const int r0 = start[n], r1 = start[n + 1];
    float z = 0.f, comp = 0.f;
    for (int r = r0; r < r1; ++r) {
        z += exbuf[r];
        if (lane < 40) comp += vbuf[(size_t)r * 40 + lane];
    }
    if (lane < 40)
        out[(size_t)n * 40 + lane] = (z > 0.f) ? comp * rsqrtf(z) : 0.f;
}

// ==================== DIAGNOSTIC PROBES (output-neutral) ====================

// probe_id_mfma: D = A*I with asymmetric integer A -> tests C/D mapping directly.
// Always spins ~250us (canary proving MFMA kernels launch); +huge if mismatch.
__global__ __launch_bounds__(64) void probe_id_mfma(float* __restrict__ scratch) {
    const int lane = threadIdx.x & 63, quad = lane >> 4, m = lane & 15;
    ABu aa, bb;
#pragma unroll
    for (int r = 0; r < 4; ++r) {
        const int k0 = quad*8 + 2*r, k1 = k0 + 1;
        const float a0 = (float)((m*31 + k0*7) % 13 - 6);   // exact small ints
        const float a1 = (float)((m*31 + k1*7) % 13 - 6);
        aa.u[r] = pack2(a0, a1);
        bb.u[r] = pack2((k0 == m) ? 1.f : 0.f, (k1 == m) ? 1.f : 0.f);
    }
    f32x4 d = {0.f, 0.f, 0.f, 0.f};
    d = __builtin_amdgcn_mfma_f32_16x16x32_bf16(aa.v, bb.v, d, 0, 0, 0);
    float diff = 0.f;
#pragma unroll
    for (int r = 0; r < 4; ++r) {
        const int row = quad*4 + r;                          // claimed C map
        const float ex = (float)((row*31 + m*7) % 13 - 6);   // A[row][col=m]
        diff = fmaxf(diff, fabsf(d[r] - ex));
    }
    scratch[lane] = diff;
    const unsigned long long bad = __ballot(diff > 0.5f);
    spin_fma(150000 + (bad ? 3000000 : 0), scratch + 64 + lane);
}

// probe_h_mfma: h-GEMM (es @ W1, K=32 zero-padded) vs scalar bf16 ref.
__global__ __launch_bounds__(64) void probe_h_mfma(
    const float* __restrict__ edge_scalars, const float* __restrict__ fck_w1,
    float* __restrict__ scratch) {
    const int lane = threadIdx.x & 63, quad = lane >> 4, m = lane & 15;
    ABu ea, bb;
    if (quad < 2) {
#pragma unroll
        for (int r = 0; r < 4; ++r) {
            const int k0 = quad*8 + 2*r;
            ea.u[r] = pack2(edge_scalars[m*16 + k0], edge_scalars[m*16 + k0 + 1]);
            bb.u[r] = pack2(fck_w1[k0*32 + m], fck_w1[(k0+1)*32 + m]);
        }
    } else { ea.u[0]=ea.u[1]=ea.u[2]=ea.u[3]=0; bb.u[0]=bb.u[1]=bb.u[2]=bb.u[3]=0; }
    f32x4 hc = {0.f, 0.f, 0.f, 0.f};
    hc = __builtin_amdgcn_mfma_f32_16x16x32_bf16(ea.v, bb.v, hc, 0, 0, 0);
    float diff = 0.f;
#pragma unroll
    for (int r = 0; r < 4; ++r) {
        const int edge = quad*4 + r;
        float ref = 0.f;
        for (int t = 0; t < 16; ++t)
            ref += b2f(f2b(edge_scalars[edge*16 + t])) * b2f(f2b(fck_w1[t*32 + m]));
        diff = fmaxf(diff, fabsf(hc[r] - ref) / (1.f + fabsf(ref)));
    }
    scratch[128 + lane] = diff;
    const unsigned long long bad = __ballot(diff > 0.02f);
    spin_fma(bad ? 3000000 : 0, scratch + 192 + lane);
}

// probe_tk_mfma: faithful copy of R8's MFMA edge_k (edges 0..63) through cst
// staging, ref-checked at the ck[28] level against the SAME staged bf16 bits.
__global__ __launch_bounds__(256) void probe_tk_mfma(
    const float* __restrict__ node_ft, const int* __restrict__ ei,
    const float* __restrict__ edge_sh, const float* __restrict__ edge_scalars,
    const float* __restrict__ fck_w1, const float* __restrict__ fck_w2,
    const int* __restrict__ flag, float* __restrict__ scratch, int E)
{
    __shared__ unsigned sL[13204];
    __shared__ int pflag;
    const int tid = threadIdx.x;
    const int w = tid >> 6, lane = tid & 63, quad = lane >> 4, m = lane & 15;
    const int is64 = *flag;
    if (tid == 0) pflag = 0;

    const int e = w * 16 + m;                   // block 0 equivalent; e < 64 <= E
    const int snd = is64 ? ei[2*e] : ei[e];
    const float4 sh4 = *(const float4*)(edge_sh + (size_t)e * 4);

    for (int idx = tid; idx < 20; idx += 256) sL[idx] = 0;
    for (int idx = tid; idx < 3072; idx += 256) {
        const int t = idx & 15, rest = idx >> 4, n = rest % 12, i = rest / 12;
        const int col = (n < 8) ? (i*8 + n) : (192 + i*4 + (n - 8));
        sL[20 + (i*12 + n)*20 + t] = pack2(fck_w2[(2*t)*320 + col], fck_w2[(2*t+1)*320 + col]);
    }
    for (int idx = tid; idx < 1024; idx += 256) {
        const int t = idx & 15, rest = idx >> 4, n = rest & 7, i = rest >> 3;
        const int col = 128 + i*8 + n;
        sL[3860 + (i*8 + n)*20 + t] = pack2(fck_w2[(2*t)*320 + col], fck_w2[(2*t+1)*320 + col]);
    }
    for (int idx = tid; idx < 1024; idx += 256) {
        const int t = idx & 15, rest = idx >> 4, n = rest & 7, i = rest >> 3;
        const int col = (n < 4) ? (256 + i*4 + n) : (288 + i*4 + (n - 4));
        sL[5140 + (i*8 + n)*20 + t] = pack2(fck_w2[(2*t)*320 + col], fck_w2[(2*t+1)*320 + col]);
    }
    for (int idx = tid; idx < 256; idx += 256) {
        const int t = idx & 7, n = idx >> 3;
        sL[6420 + n*12 + t] = pack2(fck_w1[(2*t)*32 + n], fck_w1[(2*t+1)*32 + n]);
    }

    float* pp = (float*)(sL + 6804 + w*1600);   // [16][52]
    float* hs = pp + 832;                        // hbuf[16][40] then cst[16][48]

    {
        const float* nf = node_ft + (size_t)snd * 40;
        const float4 c0 = *(const float4*)(nf + 4*quad);
        const float4 c1 = *(const float4*)(nf + 16 + 4*quad);
        pp[m*52 + 4*quad + 0] = c0.x; pp[m*52 + 4*quad + 1] = c0.y;
        pp[m*52 + 4*quad + 2] = c0.z; pp[m*52 + 4*quad + 3] = c0.w;
        const float v1[4] = {c1.x, c1.y, c1.z, c1.w};
#pragma unroll
        for (int r = 0; r < 4; ++r) {
            const int f = 4*quad + r;
            pp[m*52 + 24 + (f % 3)*8 + f/3] = v1[r];
        }
        if (quad < 2) {
            const float4 c2 = *(const float4*)(nf + 32 + 4*quad);
            const float v2[4] = {c2.x, c2.y, c2.z, c2.w};
#pragma unroll
            for (int r = 0; r < 4; ++r) {
                const int f = 16 + 4*quad + r;
                pp[m*52 + 24 + (f % 3)*8 + f/3] = v2[r];
            }
        }
    }
    __syncthreads();
#pragma unroll
    for (int ii = 0; ii < 2; ++ii) {
        const int i = quad*2 + ii;
        const float x0 = pp[m*52 + 24 + i];
        const float x1 = pp[m*52 + 32 + i];
        const float x2 = pp[m*52 + 40 + i];
        pp[m*52 + 16 + i] = (x0*sh4.y + x1*sh4.z + x2*sh4.w) * 0.57735026918962576f;
    }
    __syncthreads();

    ABu ea;
    if (quad < 2) {
        const float* esp = edge_scalars + (size_t)e*16 + quad*8;
        const float4 q0 = *(const float4*)esp;
        const float4 q1 = *(const float4*)(esp + 4);
        ea.u[0] = pack2(q0.x, q0.y); ea.u[1] = pack2(q0.z, q0.w);
        ea.u[2] = pack2(q1.x, q1.y); ea.u[3] = pack2(q1.z, q1.w);
    } else { ea.u[0] = ea.u[1] = ea.u[2] = ea.u[3] = 0; }
#pragma unroll
    for (int nt = 0; nt < 2; ++nt) {
        ABu bb;
        if (quad < 2) {
            const uint4 bv = *(const uint4*)&sL[6420 + (nt*16 + m)*12 + quad*4];
            bb.u[0] = bv.x; bb.u[1] = bv.y; bb.u[2] = bv.z; bb.u[3] = bv.w;
        } else { bb.u[0] = bb.u[1] = bb.u[2] = bb.u[3] = 0; }
        f32x4 hc = {0.f, 0.f, 0.f, 0.f};
        hc = __builtin_amdgcn_mfma_f32_16x16x32_bf16(ea.v, bb.v, hc, 0, 0, 0);
#pragma unroll
        for (int r = 0; r < 4; ++r)
            hs[(quad*4 + r)*40 + nt*16 + m] = silu_f(hc[r] * 0.25f);
    }
    __syncthreads();
    float hreg[8];
    {
        const float4 h0 = *(const float4*)&hs[m*40 + quad*8];
        const float4 h1 = *(const float4*)&hs[m*40 + quad*8 + 4];
        hreg[0]=h0.x; hreg[1]=h0.y; hreg[2]=h0.z; hreg[3]=h0.w;
        hreg[4]=h1.x; hreg[5]=h1.y; hreg[6]=h1.z; hreg[7]=h1.w;
    }
    float hloc[32];                       // snapshot for the ref (quad 0 uses it)
#pragma unroll
    for (int k = 0; k < 8; ++k) {
        hloc[k]      = hs[m*40 + k];
        hloc[8 + k]  = hs[m*40 + 8 + k];
        hloc[16 + k] = hs[m*40 + 16 + k];
        hloc[24 + k] = hs[m*40 + 24 + k];
    }
    __syncthreads();                      // hs about to be overlaid by cst

    f32x4 acc1 = {0.f,0.f,0.f,0.f};
#pragma unroll
    for (int i4 = 0; i4 < 16; i4 += 4) {
        const float4 p4 = *(const float4*)&pp[m*52 + i4];
        const float pv[4] = {p4.x, p4.y, p4.z, p4.w};
#pragma unroll
        for (int di = 0; di < 4; ++di) {
            const int i = i4 + di;
            ABu aa;
            aa.u[0] = pack2(pv[di]*hreg[0], pv[di]*hreg[1]);
            aa.u[1] = pack2(pv[di]*hreg[2], pv[di]*hreg[3]);
            aa.u[2] = pack2(pv[di]*hreg[4], pv[di]*hreg[5]);
            aa.u[3] = pack2(pv[di]*hreg[6], pv[di]*hreg[7]);
            ABu bb;
            const int row = (m < 12) ? (20 + (i*12 + m)*20) : 0;
            const uint4 bv = *(const uint4*)&sL[row + quad*4];
            bb.u[0]=bv.x; bb.u[1]=bv.y; bb.u[2]=bv.z; bb.u[3]=bv.w;
            acc1 = __builtin_amdgcn_mfma_f32_16x16x32_bf16(aa.v, bb.v, acc1, 0,0,0);
        }
    }
    f32x4 acc2 = {0.f,0.f,0.f,0.f};
#pragma unroll
    for (int i4 = 0; i4 < 8; i4 += 4) {
        const float4 p4 = *(const float4*)&pp[m*52 + 16 + i4];
        const float pv[4] = {p4.x, p4.y, p4.z, p4.w};
#pragma unroll
        for (int di = 0; di < 4; ++di) {
            const int i = i4 + di;
            ABu aa;
            aa.u[0] = pack2(pv[di]*hreg[0], pv[di]*hreg[1]);
            aa.u[1] = pack2(pv[di]*hreg[2], pv[di]*hreg[3]);
            aa.u[2] = pack2(pv[di]*hreg[4], pv[di]*hreg[5]);
            aa.u[3] = pack2(pv[di]*hreg[6], pv[di]*hreg[7]);
            ABu bb;
            const int row = (m < 8) ? (3860 + (i*8 + m)*20) : 0;
            const uint4 bv = *(const uint4*)&sL[row + quad*4];
            bb.u[0]=bv.x; bb.u[1]=bv.y; bb.u[2]=bv.z; bb.u[3]=bv.w;
            acc2 = __builtin_amdgcn_mfma_f32_16x16x32_bf16(aa.v, bb.v, acc2, 0,0,0);
        }
    }
    f32x4 acc3 = {0.f,0.f,0.f,0.f};       // c = 0 component only (sufficient test)
#pragma unroll
    for (int i4 = 0; i4 < 8; i4 += 4) {
        const float4 p4 = *(const float4*)&pp[m*52 + 24 + i4];
        const float pv[4] = {p4.x, p4.y, p4.z, p4.w};
#pragma unroll
        for (int di = 0; di < 4; ++di) {
            const int i = i4 + di;
            ABu aa;
            aa.u[0] = pack2(pv[di]*hreg[0], pv[di]*hreg[1]);
            aa.u[1] = pack2(pv[di]*hreg[2], pv[di]*hreg[3]);
            aa.u[2] = pack2(pv[di]*hreg[4], pv[di]*hreg[5]);
            aa.u[3] = pack2(pv[di]*hreg[6], pv[di]*hreg[7]);
            ABu bb;
            const int row = (m < 8) ? (5140 + (i*8 + m)*20) : 0;
            const uint4 bv = *(const uint4*)&sL[row + quad*4];
            bb.u[0]=bv.x; bb.u[1]=bv.y; bb.u[2]=bv.z; bb.u[3]=bv.w;
            acc3 = __builtin_amdgcn_mfma_f32_16x16x32_bf16(aa.v, bb.v, acc3, 0,0,0);
        }
    }

    if (m < 12) {
#pragma unroll
        for (int r = 0; r < 4; ++r) hs[(quad*4 + r)*48 + m] = acc1[r];
    }
    if (m < 8) {
#pragma unroll
        for (int r = 0; r < 4; ++r) hs[(quad*4 + r)*48 + 12 + m] = acc2[r];
#pragma unroll
        for (int r = 0; r < 4; ++r) hs[(quad*4 + r)*48 + 20 + m] = acc3[r];
    }
    __syncthreads();

    // ---- scalar ref from the SAME staged bf16 bits (quad 0, edge m) ----
    if (quad == 0) {
        float md = 0.f;
#pragma unroll 1
        for (int n = 0; n < 28; ++n) {
            float ref = 0.f;
            if (n < 12) {
                for (int i = 0; i < 16; ++i) {
                    const float p = pp[m*52 + i];
                    const int base = 20 + (i*12 + n)*20;
                    for (int k = 0; k < 32; ++k)
                        ref += b2f(f2b(p * hloc[k])) * bsel(sL[base + (k >> 1)], k & 1);
                }
            } else if (n < 20) {
                const int o = n - 12;
                for (int i = 0; i < 8; ++i) {
                    const float p = pp[m*52 + 16 + i];
                    const int base = 3860 + (i*8 + o)*20;
                    for (int k = 0; k < 32; ++k)
                        ref += b2f(f2b(p * hloc[k])) * bsel(sL[base + (k >> 1)], k & 1);
                }
            } else {
                const int o = n - 20;
                for (int i = 0; i < 8; ++i) {
                    const float p = pp[m*52 + 24 + i];
                    const int base = 5140 + (i*8 + o)*20;
                    for (int k = 0; k < 32; ++k)
                        ref += b2f(f2b(p * hloc[k])) * bsel(sL[base + (k >> 1)], k & 1);
                }
            }
            const float got = (n < 20) ? hs[m*48 + n] : hs[m*48 + 20 + (n - 20)];
            md = fmaxf(md, fabsf(got - ref) / (1.f + fabsf(ref)));
        }
        scratch[320 + w*16 + m] = md;
        if (md > 0.02f) pflag = 1;
    }
    __syncthreads();
    spin_fma(pflag ? 5000000 : 0, scratch + 400 + tid);
}

extern "C" void kernel_launch(void* const* d_in, const int* in_sizes, int n_in,
                              void* d_out, int out_size, void* d_ws, size_t ws_size,
                              hipStream_t stream) {
    const float* node_ft      = (const float*)d_in[0];
    const int*   edge_index   = (const int*)  d_in[1];
    const float* edge_sh      = (const float*)d_in[2];
    const float* edge_scalars = (const float*)d_in[3];
    const float* w_q_s        = (const float*)d_in[4];
    const float* w_q_v        = (const float*)d_in[5];
    const float* fck_w1       = (const float*)d_in[6];
    const float* fck_w2       = (const float*)d_in[7];
    const float* fcv_w1       = (const float*)d_in[8];
    const float* fcv_w2       = (const float*)d_in[9];
    const float* wdot_s       = (const float*)d_in[10];
    const float* wdot_v       = (const float*)d_in[11];

    const int N = in_sizes[0] / 40;
    const int E = in_sizes[2] / 4;

    float* ws    = (float*)d_ws;
    float* qd    = ws;                               // N*20
    int*   cnt   = (int*)(ws + (size_t)N * 20);      // N
    int*   start = cnt + N;                          // N+1
    int*   curs  = start + N + 1;                    // N
    int*   flg   = curs + N;                         // 1
    size_t off   = (size_t)N * 20 + N + (N + 1) + N + 1;
    off = (off + 3) & ~(size_t)3;                    // 16B align
    float* exbuf  = ws + off;                        // E
    float* sabuf  = exbuf + E;                       // E
    int*   posbuf = (int*)(sabuf + E);               // E
    float* vbuf   = (float*)(posbuf + E);            // E*40
    float* pscr   = vbuf + (size_t)E * 40;           // probe scratch (~1KB)

    float* out = (float*)d_out;

    hipLaunchKernelGGL(node_pre, dim3((N + 255) / 256), dim3(256), 0, stream,
                       node_ft, edge_index, w_q_s, w_q_v, wdot_s, wdot_v,
                       qd, cnt, flg, N, E);
    hipLaunchKernelGGL(count_edges, dim3((E + 255) / 256), dim3(256), 0, stream,
                       edge_index, cnt, flg, E);
    hipLaunchKernelGGL(scan_kernel, dim3(1), dim3(1024), 0, stream,
                       cnt, start, curs, N);
    hipLaunchKernelGGL(edge_k, dim3((E + BS - 1) / BS), dim3(BS), 0, stream,
                       node_ft, edge_index, edge_sh, edge_scalars,
                       fck_w1, fck_w2, qd, curs, exbuf, sabuf, posbuf, flg, N, E);
    hipLaunchKernelGGL(edge_v_a, dim3((E + BS - 1) / BS), dim3(BS), 0, stream,
                       node_ft, edge_index, edge_sh, edge_scalars,
                       fcv_w1, fcv_w2, sabuf, posbuf, vbuf, flg, E);
    hipLaunchKernelGGL(edge_v_b, dim3((E + BS - 1) / BS), dim3(BS), 0, stream,
                       node_ft, edge_index, edge_sh, edge_scalars,
                       fcv_w1, fcv_w2, sabuf, posbuf, vbuf, flg, E);
    hipLaunchKernelGGL(node_reduce, dim3((N + 3) / 4), dim3(256), 0, stream,
                       start, exbuf, vbuf, out, N);

    // ---- diagnostics (after output is produced; write only to pscr) ----
    hipLaunchKernelGGL(probe_id_mfma, dim3(1), dim3(64), 0, stream, pscr);
    hipLaunchKernelGGL(probe_h_mfma, dim3(1), dim3(64), 0, stream,
                       edge_scalars, fck_w1, pscr);
    hipLaunchKernelGGL(probe_tk_mfma, dim3(1), dim3(256), 0, stream,
                       node_ft, edge_index, edge_sh, edge_scalars,
                       fck_w1, fck_w2, flg, pscr, E);
}